// Round 11
// baseline (939.845 us; speedup 1.0000x reference)
//
#include <hip/hip_runtime.h>
#include <hip/hip_bf16.h>
#include <math.h>

using bf16 = __hip_bfloat16;
typedef short bf16x8 __attribute__((ext_vector_type(8)));
typedef float f32x4 __attribute__((ext_vector_type(4)));
typedef float f32x16 __attribute__((ext_vector_type(16)));

static constexpr int  TOK     = 100352;     // 32*56*56 tokens
static constexpr long QKV_SEG = 38535168L;  // TOK*384 elements per q/k/v segment

__device__ __forceinline__ float bf2f(short u) {
    return __uint_as_float(((unsigned)(unsigned short)u) << 16);
}
// fast RNE float->bf16
__device__ __forceinline__ short f2bs(float x) {
    unsigned u = __float_as_uint(x);
    u += 0x7FFF + ((u >> 16) & 1);
    return (short)(u >> 16);
}
// 1-ulp reciprocal (v_rcp_f32)
__device__ __forceinline__ float fast_rcp(float x) {
    float r;
    asm volatile("v_rcp_f32 %0, %1" : "=v"(r) : "v"(x));
    return r;
}
// async global->LDS, 16B per lane. LDS dest must be uniform base + lane*16.
__device__ __forceinline__ void gload16(const void* g, void* l) {
    __builtin_amdgcn_global_load_lds(
        (const __attribute__((address_space(1))) unsigned int*)g,
        (__attribute__((address_space(3))) unsigned int*)l, 16, 0, 0);
}
// tanh-form GELU: x * sigmoid(1.5957691x + 0.071354816x^3); max |err| ~1e-3
__device__ __forceinline__ float gelu_fast(float x) {
    const float x2 = x * x;
    const float t1 = x * x2;
    const float y  = fmaf(0.071354816222f, t1, 1.5957691216f * x);
    const float e  = __expf(-y);
    return x * fast_rcp(1.f + e);
}

// ---------------------------------------------------------------------------
// Pre-convert all fp32 weights to bf16 (once per launch, ~7MB traffic).
// layout: qkv[0,442368) proj[442368,589824) fc1[589824,1179648) fc2[1179648,1769472)
// ---------------------------------------------------------------------------
__global__ __launch_bounds__(256)
void convert_w_kernel(const float* __restrict__ qkv_w, const float* __restrict__ proj_w,
                      const float* __restrict__ fc1_w, const float* __restrict__ fc2_w,
                      bf16* __restrict__ out)
{
    const int i4 = (blockIdx.x * 256 + threadIdx.x) * 4;
    if (i4 >= 1769472) return;
    const float* src; int off;
    if (i4 < 442368)       { src = qkv_w;  off = i4; }
    else if (i4 < 589824)  { src = proj_w; off = i4 - 442368; }
    else if (i4 < 1179648) { src = fc1_w;  off = i4 - 589824; }
    else                   { src = fc2_w;  off = i4 - 1179648; }
    const float4 v = *(const float4*)&src[off];
    out[i4+0] = __float2bfloat16(v.x);
    out[i4+1] = __float2bfloat16(v.y);
    out[i4+2] = __float2bfloat16(v.z);
    out[i4+3] = __float2bfloat16(v.w);
}

// ---------------------------------------------------------------------------
// LayerNorm over C=384, one wave per token. WINDOWED: dst order is
// (b, window, intra-window) after roll(-3,-3); source is original x.
// ---------------------------------------------------------------------------
template<bool WINDOWED>
__global__ __launch_bounds__(256)
void ln_kernel(const float* __restrict__ x, const float* __restrict__ gw,
               const float* __restrict__ gb, bf16* __restrict__ out)
{
    const int wave = threadIdx.x >> 6;
    const int lane = threadIdx.x & 63;
    const long t = (long)blockIdx.x * 4 + wave;
    size_t src;
    if (WINDOWED) {
        int bb = (int)(t / 3136); int rem = (int)(t - (long)bb * 3136);
        int wIdx = rem / 49;      int n = rem - wIdx * 49;
        int wh = wIdx >> 3, ww = wIdx & 7;
        int yi = n / 7,     xi = n - yi * 7;
        int r = wh * 7 + yi + 3; if (r >= 56) r -= 56;
        int c = ww * 7 + xi + 3; if (c >= 56) c -= 56;
        src = ((size_t)bb * 3136 + (size_t)r * 56 + c) * 384;
    } else {
        src = (size_t)t * 384;
    }
    float v[6]; float s = 0.f, sq = 0.f;
    #pragma unroll
    for (int kk = 0; kk < 6; ++kk) {
        v[kk] = x[src + lane + 64 * kk];
        s += v[kk]; sq += v[kk] * v[kk];
    }
    #pragma unroll
    for (int o = 32; o > 0; o >>= 1) { s += __shfl_xor(s, o); sq += __shfl_xor(sq, o); }
    const float m   = s * (1.f / 384.f);
    const float var = sq * (1.f / 384.f) - m * m;
    const float rs  = rsqrtf(var + 1e-5f);
    #pragma unroll
    for (int kk = 0; kk < 6; ++kk) {
        int ch = lane + 64 * kk;
        out[(size_t)t * 384 + ch] = __float2bfloat16((v[kk] - m) * rs * gw[ch] + gb[ch]);
    }
}

// ---------------------------------------------------------------------------
// GEMM: C[M,N] = A[M,K](bf16) @ W[N,K]^T(bf16) + bias.
// BM=256 x BN=128 tile, BK=64, 8 waves, wave tile 64x64 as 2x2 fragments of
// the 32x32x16 MFMA (HALF the instruction count of 16x16x32, 15% higher pipe
// ceiling, same LDS bytes). C/D layout (HW-verified): col(token)=lane&31,
// row(feature)=(reg&3)+8*(reg>>2)+4*(lane>>5) -> lane holds 1 token x 4
// chunks of 4 consecutive features -> vector epilogue, 2 token-divisions.
// Single-buffered 48 KB LDS, T2 XOR swizzle both-sides, swapped operands.
// ---------------------------------------------------------------------------
template<int MODE, int K>
__global__ __launch_bounds__(512)
void gemm_bt(const bf16* __restrict__ A, const bf16* __restrict__ W,
             const float* __restrict__ bias, bf16* __restrict__ outb,
             float* __restrict__ outf, const float* __restrict__ resid,
             int tilesN)
{
    __shared__ bf16 As[256 * 64];   // 32 KB
    __shared__ bf16 Bs[128 * 64];   // 16 KB
    const int nwg = gridDim.x;
    const int b0  = blockIdx.x;
    const int swz = (b0 & 7) * (nwg >> 3) + (b0 >> 3);
    const int tm = swz / tilesN;
    const int tn = swz - tm * tilesN;
    const int tid  = threadIdx.x;
    const int lane = tid & 63;
    const int wid  = tid >> 6;
    const int wr = (wid >> 1) << 6;   // token offset of wave tile: 0..192
    const int wc = (wid & 1) << 6;    // feature offset of wave tile: 0/64
    const int sr = tid >> 3;          // staging row 0..63
    const int sc = (tid & 7) * 8;     // staging LDS col, step 8
    const int scs = sc ^ ((sr & 7) << 3);   // pre-swizzled SOURCE col

    f32x16 acc[2][2];                 // [ni][mi] 32x32 fragments
    #pragma unroll
    for (int i = 0; i < 2; ++i)
        #pragma unroll
        for (int j = 0; j < 2; ++j) acc[i][j] = (f32x16)0.0f;

    const int am0 = tm * 256;
    const int bn0 = tn * 128;
    const bf16* Ab = A + (size_t)am0 * K + scs;   // + row*K + k0
    const bf16* Wb = W + (size_t)bn0 * K + scs;

    const int rophase = (lane & 7) << 3;   // read-side swizzle phase
    const int kb2     = (lane >> 5) << 3;  // 0 or 8 (K-half within 16-slice)
    const int l31     = lane & 31;

    for (int k0 = 0; k0 < K; k0 += 64) {
        #pragma unroll
        for (int p = 0; p < 4; ++p) {
            const int row = p * 64 + sr;
            gload16(&Ab[(size_t)row * K + k0], &As[row * 64 + sc]);
        }
        #pragma unroll
        for (int p = 0; p < 2; ++p) {
            const int row = p * 64 + sr;
            gload16(&Wb[(size_t)row * K + k0], &Bs[row * 64 + sc]);
        }
        __syncthreads();
        #pragma unroll
        for (int ks = 0; ks < 4; ++ks) {            // 4 K-slices of 16
            const int kofs = (ks * 16 + kb2) ^ rophase;
            bf16x8 aF[2], bF[2];
            #pragma unroll
            for (int mi = 0; mi < 2; ++mi)
                aF[mi] = *(const bf16x8*)&As[(wr + mi * 32 + l31) * 64 + kofs];
            #pragma unroll
            for (int ni = 0; ni < 2; ++ni)
                bF[ni] = *(const bf16x8*)&Bs[(wc + ni * 32 + l31) * 64 + kofs];
            #pragma unroll
            for (int ni = 0; ni < 2; ++ni)
                #pragma unroll
                for (int mi = 0; mi < 2; ++mi)
                    acc[ni][mi] = __builtin_amdgcn_mfma_f32_32x32x16_bf16(
                        bF[ni], aF[mi], acc[ni][mi], 0, 0, 0);
        }
        __syncthreads();
    }

    // ---- epilogue: lane holds token gm x feature chunks gn0..gn0+3 ----
    const int g2 = (lane >> 5) << 2;   // 0 or 4
    int    gnc[2][4];
    float4 bvc[2][4];
    #pragma unroll
    for (int ni = 0; ni < 2; ++ni)
        #pragma unroll
        for (int q = 0; q < 4; ++q) {
            gnc[ni][q] = bn0 + wc + ni * 32 + q * 8 + g2;   // 4-aligned
            bvc[ni][q] = *(const float4*)&bias[gnc[ni][q]];
        }

    #pragma unroll
    for (int mi = 0; mi < 2; ++mi) {
        const int gm = am0 + wr + mi * 32 + l31;
        // per-token scatter info (hoisted)
        size_t tokdst = 0;
        int wwi = 0, ntok = 0;
        if (MODE == 0) {
            wwi = gm / 49; ntok = gm - wwi * 49;
        } else if (MODE == 1) {
            int bb = gm / 3136; int rem = gm - bb * 3136;
            int wIdx = rem / 49; int n = rem - wIdx * 49;
            int wh = wIdx >> 3, ww2 = wIdx & 7;
            int yi = n / 7,     xi = n - yi * 7;
            int rr = wh * 7 + yi + 3; if (rr >= 56) rr -= 56;
            int cc = ww2 * 7 + xi + 3; if (cc >= 56) cc -= 56;
            tokdst = ((size_t)bb * 3136 + (size_t)rr * 56 + cc) * 384;
        }
        #pragma unroll
        for (int ni = 0; ni < 2; ++ni) {
            #pragma unroll
            for (int q = 0; q < 4; ++q) {
                const int gn0 = gnc[ni][q];
                float vals[4];
                #pragma unroll
                for (int r = 0; r < 4; ++r)
                    vals[r] = acc[ni][mi][q * 4 + r] + ((const float*)&bvc[ni][q])[r];

                if (MODE == 0) {
                    const int s3 = gn0 / 384; const int rem = gn0 - s3 * 384;
                    const int hh = rem >> 5, d0 = rem & 31;
                    size_t dst = (size_t)s3 * QKV_SEG
                               + ((size_t)(wwi * 12 + hh) * 49 + ntok) * 32 + d0;
                    union { short h4[4]; uint2 u2; } pk;
                    if (s3 == 0) {
                        #pragma unroll
                        for (int r = 0; r < 4; ++r)
                            pk.h4[r] = f2bs(vals[r] * 0.17677669529663687f);
                    } else {
                        #pragma unroll
                        for (int r = 0; r < 4; ++r) pk.h4[r] = f2bs(vals[r]);
                    }
                    *(uint2*)&outb[dst] = pk.u2;
                } else if (MODE == 1) {
                    size_t dst = tokdst + gn0;
                    const float4 rv = *(const float4*)&resid[dst];
                    float4 ov;
                    ov.x = rv.x + vals[0]; ov.y = rv.y + vals[1];
                    ov.z = rv.z + vals[2]; ov.w = rv.w + vals[3];
                    *(float4*)&outf[dst] = ov;
                } else if (MODE == 2) {
                    union { short h4[4]; uint2 u2; } pk;
                    #pragma unroll
                    for (int r = 0; r < 4; ++r) pk.h4[r] = f2bs(gelu_fast(vals[r]));
                    *(uint2*)&outb[(size_t)gm * 1536 + gn0] = pk.u2;
                } else {
                    size_t dst = (size_t)gm * 384 + gn0;
                    const float4 rv = *(const float4*)&resid[dst];
                    float4 ov;
                    ov.x = rv.x + vals[0]; ov.y = rv.y + vals[1];
                    ov.z = rv.z + vals[2]; ov.w = rv.w + vals[3];
                    *(float4*)&outf[dst] = ov;
                }
            }
        }
    }
}

// ---------------------------------------------------------------------------
// MFMA windowed attention. 4 waves/block, one (window,head) per wave.
// Swapped QK^T: S^T = mfma(A=K, B=Q) -> lane owns query col i. Softmax:
// 16 in-lane + shfl_xor(16,32). P -> LDS (XOR-swizzled). PV: O^T = mfma(V^T, P).
// ---------------------------------------------------------------------------
__global__ __launch_bounds__(256)
void attn_mfma(const bf16* __restrict__ q, const bf16* __restrict__ k,
               const bf16* __restrict__ v, const float* __restrict__ table,
               bf16* __restrict__ o)
{
    __shared__ bf16  vt_s[4][2048];   // per wave: V^T [32 d][64 j], swizzled
    __shared__ bf16  p_s[4][4096];    // per wave: P   [64 i][64 j], swizzled
    __shared__ float tbl_s[4][169];

    const int tid  = threadIdx.x;
    const int wid  = tid >> 6;
    const int lane = tid & 63;
    const int li = lane & 15, g = lane >> 4;
    const int gwh = blockIdx.x * 4 + wid;       // window*12 + head
    const int w = gwh / 12, h = gwh - w * 12;
    const int wIdx = w & 63;
    const int bh = wIdx >> 3, bw = wIdx & 7;
    const size_t base = (size_t)gwh * 1568;

    char* vt = (char*)vt_s[wid];
    char* ps = (char*)p_s[wid];

    for (int t = lane; t < 169; t += 64) tbl_s[wid][t] = table[t * 12 + h];

    {
        const int4 z = {0, 0, 0, 0};
        #pragma unroll
        for (int t = 0; t < 4; ++t) ((int4*)vt)[t * 64 + lane] = z;
        for (int t = lane; t < 196; t += 64) {
            const int j = t >> 2, d0 = (t & 3) * 8;
            bf16x8 row = *(const bf16x8*)&v[base + (size_t)j * 32 + d0];
            #pragma unroll
            for (int u = 0; u < 8; ++u) {
                const int d = d0 + u;
                int off = (d << 7) + (j << 1);
                off ^= (d & 7) << 4;
                *(short*)(vt + off) = row[u];
            }
        }
    }

    // QK^T (swapped): acc[mj][ni] = S^T[j][i]
    bf16x8 aK[4], bQ[4];
    const int koff = g * 8;
    #pragma unroll
    for (int mj = 0; mj < 4; ++mj)
        aK[mj] = *(const bf16x8*)&k[base + (size_t)(mj * 16 + li) * 32 + koff];
    #pragma unroll
    for (int ni = 0; ni < 4; ++ni)
        bQ[ni] = *(const bf16x8*)&q[base + (size_t)(ni * 16 + li) * 32 + koff];

    f32x4 acc[4][4];
    #pragma unroll
    for (int i = 0; i < 4; ++i)
        #pragma unroll
        for (int j = 0; j < 4; ++j) acc[i][j] = (f32x4)0.0f;
    #pragma unroll
    for (int mj = 0; mj < 4; ++mj)
        #pragma unroll
        for (int ni = 0; ni < 4; ++ni)
            acc[mj][ni] = __builtin_amdgcn_mfma_f32_16x16x32_bf16(
                aK[mj], bQ[ni], acc[mj][ni], 0, 0, 0);

    // softmax over j per query i
    const bool bndH = (bh == 7), bndW = (bw == 7);
    #pragma unroll
    for (int ni = 0; ni < 4; ++ni) {
        const int i = ni * 16 + li;
        const int yi = i / 7, xi = i - yi * 7;
        const int ri = (bndH ? (yi < 4 ? 3 : 6) : 0) + (bndW ? (xi < 4 ? 1 : 2) : 0);
        float mx = -1e30f;
        #pragma unroll
        for (int mj = 0; mj < 4; ++mj)
            #pragma unroll
            for (int r = 0; r < 4; ++r) {
                const int j = mj * 16 + g * 4 + r;
                const int yj = j / 7, xj = j - yj * 7;
                int ridx = (yi - yj + 6) * 13 + (xi - xj + 6);
                ridx = max(0, min(168, ridx));
                float val = acc[mj][ni][r] + tbl_s[wid][ridx];
                const int rj = (bndH ? (yj < 4 ? 3 : 6) : 0) + (bndW ? (xj < 4 ? 1 : 2) : 0);
                if (ri != rj) val -= 100.f;
                if (j >= 49) val = -1e30f;
                acc[mj][ni][r] = val;
                mx = fmaxf(mx, val);
            }
        mx = fmaxf(mx, __shfl_xor(mx, 16));
        mx = fmaxf(mx, __shfl_xor(mx, 32));
        float sum = 0.f;
        #pragma unroll
        for (int mj = 0; mj < 4; ++mj)
            #pragma unroll
            for (int r = 0; r < 4; ++r) {
                const float p = __expf(acc[mj][ni][r] - mx);
                acc[mj][ni][r] = p; sum += p;
            }
        sum += __shfl_xor(sum, 16);
        sum += __shfl_xor(sum, 32);
        const float inv = 1.f / sum;
        #pragma unroll
        for (int mj = 0; mj < 4; ++mj) {
            union { short h4[4]; uint2 u2; } pk;
            #pragma unroll
            for (int r = 0; r < 4; ++r) pk.h4[r] = f2bs(acc[mj][ni][r] * inv);
            int off = (i << 7) + ((mj * 16 + g * 4) << 1);
            off ^= (i & 7) << 4;
            *(uint2*)(ps + off) = pk.u2;
        }
    }

    // PV: acc2[md][ni] = O^T[d][i]
    f32x4 acc2[2][4];
    #pragma unroll
    for (int i = 0; i < 2; ++i)
        #pragma unroll
        for (int j = 0; j < 4; ++j) acc2[i][j] = (f32x4)0.0f;
    #pragma unroll
    for (int kk = 0; kk < 2; ++kk) {
        bf16x8 aV[2], bP[4];
        #pragma unroll
        for (int md = 0; md < 2; ++md) {
            const int d = md * 16 + li;
            int off = (d << 7) + kk * 64 + g * 16;
            off ^= (d & 7) << 4;
            aV[md] = *(const bf16x8*)(vt + off);
        }
        #pragma unroll
        for (int ni = 0; ni < 4; ++ni) {
            const int i = ni * 16 + li;
            int off = (i << 7) + kk * 64 + g * 16;
            off ^= (i & 7) << 4;
            bP[ni] = *(const bf16x8*)(ps + off);
        }
        #pragma unroll
        for (int md = 0; md < 2; ++md)
            #pragma unroll
            for (int ni = 0; ni < 4; ++ni)
                acc2[md][ni] = __builtin_amdgcn_mfma_f32_16x16x32_bf16(
                    aV[md], bP[ni], acc2[md][ni], 0, 0, 0);
    }

    // store O[i][d]
    const size_t obase = (size_t)w * 49 * 384 + h * 32;
    #pragma unroll
    for (int ni = 0; ni < 4; ++ni) {
        const int i = ni * 16 + li;
        if (i < 49) {
            #pragma unroll
            for (int md = 0; md < 2; ++md) {
                const int d0 = md * 16 + g * 4;
                union { short h4[4]; uint2 u2; } pk;
                #pragma unroll
                for (int r = 0; r < 4; ++r) pk.h4[r] = f2bs(acc2[md][ni][r]);
                *(uint2*)&o[obase + (size_t)i * 384 + d0] = pk.u2;
            }
        }
    }
}

// ---------------------------------------------------------------------------
extern "C" void kernel_launch(void* const* d_in, const int* in_sizes, int n_in,
                              void* d_out, int out_size, void* d_ws, size_t ws_size,
                              hipStream_t stream) {
    const float* x      = (const float*)d_in[0];
    const float* n1w    = (const float*)d_in[1];
    const float* n1b    = (const float*)d_in[2];
    const float* qkv_w  = (const float*)d_in[3];
    const float* qkv_b  = (const float*)d_in[4];
    const float* table  = (const float*)d_in[5];
    const float* proj_w = (const float*)d_in[6];
    const float* proj_b = (const float*)d_in[7];
    const float* n2w    = (const float*)d_in[8];
    const float* n2b    = (const float*)d_in[9];
    const float* fc1_w  = (const float*)d_in[10];
    const float* fc1_b  = (const float*)d_in[11];
    const float* fc2_w  = (const float*)d_in[12];
    const float* fc2_b  = (const float*)d_in[13];
    float* out = (float*)d_out;

    char* ws = (char*)d_ws;
    bf16* buf0 = (bf16*)ws;                              // TOK*384 bf16
    bf16* buf1 = (bf16*)(ws + 77070336);                 // qkv / hid
    bf16* wb   = (bf16*)(ws + 77070336 + 308281344);     // bf16 weights

    convert_w_kernel<<<1728, 256, 0, stream>>>(qkv_w, proj_w, fc1_w, fc2_w, wb);
    // 1) LN1 + roll + window partition -> buf0
    ln_kernel<true><<<TOK / 4, 256, 0, stream>>>(x, n1w, n1b, buf0);
    // 2) QKV GEMM -> buf1 (q|k|v, head-major); 392 M-tiles x 9 N-tiles
    gemm_bt<0, 384><<<392 * 9, 512, 0, stream>>>(buf0, wb, qkv_b,
                                                 buf1, nullptr, nullptr, 9);
    // 3) MFMA windowed attention -> buf0
    attn_mfma<<<2048 * 12 / 4, 256, 0, stream>>>(buf1, buf1 + QKV_SEG,
                                                 buf1 + 2 * QKV_SEG, table, buf0);
    // 4) proj GEMM + reverse/roll + residual -> out; 3 N-tiles
    gemm_bt<1, 384><<<392 * 3, 512, 0, stream>>>(buf0, wb + 442368, proj_b,
                                                 nullptr, out, x, 3);
    // 5) LN2(y) -> buf0
    ln_kernel<false><<<TOK / 4, 256, 0, stream>>>(out, n2w, n2b, buf0);
    // 6) fc1 + GELU -> buf1; 12 N-tiles
    gemm_bt<2, 384><<<392 * 12, 512, 0, stream>>>(buf0, wb + 589824, fc1_b,
                                                  buf1, nullptr, nullptr, 12);
    // 7) fc2 + residual (in-place on out); K=1536, 3 N-tiles
    gemm_bt<3, 1536><<<392 * 3, 512, 0, stream>>>(buf1, wb + 1179648, fc2_b,
                                                  nullptr, out, out, 3);
}

// Round 12
// 879.037 us; speedup vs baseline: 1.0692x; 1.0692x over previous
//
#include <hip/hip_runtime.h>
#include <hip/hip_bf16.h>
#include <math.h>

using bf16 = __hip_bfloat16;
typedef short bf16x8 __attribute__((ext_vector_type(8)));
typedef float f32x4 __attribute__((ext_vector_type(4)));

static constexpr int  TOK     = 100352;     // 32*56*56 tokens
static constexpr long QKV_SEG = 38535168L;  // TOK*384 elements per q/k/v segment

__device__ __forceinline__ float bf2f(short u) {
    return __uint_as_float(((unsigned)(unsigned short)u) << 16);
}
// fast RNE float->bf16
__device__ __forceinline__ short f2bs(float x) {
    unsigned u = __float_as_uint(x);
    u += 0x7FFF + ((u >> 16) & 1);
    return (short)(u >> 16);
}
// 1-ulp reciprocal (v_rcp_f32)
__device__ __forceinline__ float fast_rcp(float x) {
    float r;
    asm volatile("v_rcp_f32 %0, %1" : "=v"(r) : "v"(x));
    return r;
}
// async global->LDS, 16B per lane. LDS dest must be uniform base + lane*16.
__device__ __forceinline__ void gload16(const void* g, void* l) {
    __builtin_amdgcn_global_load_lds(
        (const __attribute__((address_space(1))) unsigned int*)g,
        (__attribute__((address_space(3))) unsigned int*)l, 16, 0, 0);
}
// tanh-form GELU: x * sigmoid(1.5957691x + 0.071354816x^3); max |err| ~1e-3
__device__ __forceinline__ float gelu_fast(float x) {
    const float x2 = x * x;
    const float t1 = x * x2;
    const float y  = fmaf(0.071354816222f, t1, 1.5957691216f * x);
    const float e  = __expf(-y);
    return x * fast_rcp(1.f + e);
}

// ---------------------------------------------------------------------------
// Pre-convert all fp32 weights to bf16 (once per launch, ~7MB traffic).
// layout: qkv[0,442368) proj[442368,589824) fc1[589824,1179648) fc2[1179648,1769472)
// ---------------------------------------------------------------------------
__global__ __launch_bounds__(256)
void convert_w_kernel(const float* __restrict__ qkv_w, const float* __restrict__ proj_w,
                      const float* __restrict__ fc1_w, const float* __restrict__ fc2_w,
                      bf16* __restrict__ out)
{
    const int i4 = (blockIdx.x * 256 + threadIdx.x) * 4;
    if (i4 >= 1769472) return;
    const float* src; int off;
    if (i4 < 442368)       { src = qkv_w;  off = i4; }
    else if (i4 < 589824)  { src = proj_w; off = i4 - 442368; }
    else if (i4 < 1179648) { src = fc1_w;  off = i4 - 589824; }
    else                   { src = fc2_w;  off = i4 - 1179648; }
    const float4 v = *(const float4*)&src[off];
    out[i4+0] = __float2bfloat16(v.x);
    out[i4+1] = __float2bfloat16(v.y);
    out[i4+2] = __float2bfloat16(v.z);
    out[i4+3] = __float2bfloat16(v.w);
}

// ---------------------------------------------------------------------------
// LayerNorm over C=384, one wave per token. WINDOWED: dst order is
// (b, window, intra-window) after roll(-3,-3); source is original x.
// ---------------------------------------------------------------------------
template<bool WINDOWED>
__global__ __launch_bounds__(256)
void ln_kernel(const float* __restrict__ x, const float* __restrict__ gw,
               const float* __restrict__ gb, bf16* __restrict__ out)
{
    const int wave = threadIdx.x >> 6;
    const int lane = threadIdx.x & 63;
    const long t = (long)blockIdx.x * 4 + wave;
    size_t src;
    if (WINDOWED) {
        int bb = (int)(t / 3136); int rem = (int)(t - (long)bb * 3136);
        int wIdx = rem / 49;      int n = rem - wIdx * 49;
        int wh = wIdx >> 3, ww = wIdx & 7;
        int yi = n / 7,     xi = n - yi * 7;
        int r = wh * 7 + yi + 3; if (r >= 56) r -= 56;
        int c = ww * 7 + xi + 3; if (c >= 56) c -= 56;
        src = ((size_t)bb * 3136 + (size_t)r * 56 + c) * 384;
    } else {
        src = (size_t)t * 384;
    }
    float v[6]; float s = 0.f, sq = 0.f;
    #pragma unroll
    for (int kk = 0; kk < 6; ++kk) {
        v[kk] = x[src + lane + 64 * kk];
        s += v[kk]; sq += v[kk] * v[kk];
    }
    #pragma unroll
    for (int o = 32; o > 0; o >>= 1) { s += __shfl_xor(s, o); sq += __shfl_xor(sq, o); }
    const float m   = s * (1.f / 384.f);
    const float var = sq * (1.f / 384.f) - m * m;
    const float rs  = rsqrtf(var + 1e-5f);
    #pragma unroll
    for (int kk = 0; kk < 6; ++kk) {
        int ch = lane + 64 * kk;
        out[(size_t)t * 384 + ch] = __float2bfloat16((v[kk] - m) * rs * gw[ch] + gb[ch]);
    }
}

// ---------------------------------------------------------------------------
// GEMM: C[M,N] = A[M,K](bf16) @ W[N,K]^T(bf16) + bias.  (round-10 structure)
// BM=256 x BN=128 tile, BK=64, 8 waves, wave tile 64x64 (16x16x32 MFMA,
// 4x4 frags). Single-buffered 48 KB LDS; T2 XOR swizzle both-sides (conflict
// free); swapped MFMA operands -> lane holds 4 consecutive output features;
// 32-bit epilogue math. MODE 2 hid stream stored NON-TEMPORAL (301 MB,
// single-consumer, >L2 -> keep L2 for A-panel reuse).
// ---------------------------------------------------------------------------
template<int MODE, int K>
__global__ __launch_bounds__(512)
void gemm_bt(const bf16* __restrict__ A, const bf16* __restrict__ W,
             const float* __restrict__ bias, bf16* __restrict__ outb,
             float* __restrict__ outf, const float* __restrict__ resid,
             int tilesN)
{
    __shared__ bf16 As[256 * 64];   // 32 KB
    __shared__ bf16 Bs[128 * 64];   // 16 KB
    const int nwg = gridDim.x;
    const int b0  = blockIdx.x;
    const int swz = (b0 & 7) * (nwg >> 3) + (b0 >> 3);
    const int tm = swz / tilesN;
    const int tn = swz - tm * tilesN;
    const int tid  = threadIdx.x;
    const int lane = tid & 63;
    const int wid  = tid >> 6;
    const int wr = (wid >> 1) << 6;   // M offset of wave tile: 0..192
    const int wc = (wid & 1) << 6;    // N offset of wave tile: 0/64
    const int sr = tid >> 3;          // staging row 0..63
    const int sc = (tid & 7) * 8;     // staging LDS col, step 8
    const int scs = sc ^ ((sr & 7) << 3);   // pre-swizzled SOURCE col

    f32x4 acc[4][4];                  // [nf][mf]
    #pragma unroll
    for (int i = 0; i < 4; ++i)
        #pragma unroll
        for (int j = 0; j < 4; ++j) acc[i][j] = (f32x4)0.0f;

    const int am0 = tm * 256;
    const int bn0 = tn * 128;
    const bf16* Ab = A + (size_t)am0 * K + scs;   // + row*K + k0
    const bf16* Wb = W + (size_t)bn0 * K + scs;

    const int rophase = (lane & 7) << 3;   // read-side swizzle phase
    const int kbase   = (lane >> 4) * 8;

    for (int k0 = 0; k0 < K; k0 += 64) {
        #pragma unroll
        for (int p = 0; p < 4; ++p) {
            const int row = p * 64 + sr;
            gload16(&Ab[(size_t)row * K + k0], &As[row * 64 + sc]);
        }
        #pragma unroll
        for (int p = 0; p < 2; ++p) {
            const int row = p * 64 + sr;
            gload16(&Wb[(size_t)row * K + k0], &Bs[row * 64 + sc]);
        }
        __syncthreads();
        #pragma unroll
        for (int kk = 0; kk < 2; ++kk) {
            const int kofs = (kk * 32 + kbase) ^ rophase;
            bf16x8 aF[4], bF[4];
            #pragma unroll
            for (int mi = 0; mi < 4; ++mi)
                aF[mi] = *(const bf16x8*)&As[(wr + mi * 16 + (lane & 15)) * 64 + kofs];
            #pragma unroll
            for (int ni = 0; ni < 4; ++ni)
                bF[ni] = *(const bf16x8*)&Bs[(wc + ni * 16 + (lane & 15)) * 64 + kofs];
            #pragma unroll
            for (int ni = 0; ni < 4; ++ni)
                #pragma unroll
                for (int mi = 0; mi < 4; ++mi)
                    acc[ni][mi] = __builtin_amdgcn_mfma_f32_16x16x32_bf16(
                        bF[ni], aF[mi], acc[ni][mi], 0, 0, 0);
        }
        __syncthreads();
    }

    // ---- epilogue: lane holds features gn0..gn0+3 at token gm (32-bit math) ----
    const int g4 = (lane >> 4) << 2;
    int    gn0c[4];
    float4 bvc[4];
    #pragma unroll
    for (int nf = 0; nf < 4; ++nf) {
        gn0c[nf] = bn0 + wc + nf * 16 + g4;     // 4-aligned
        bvc[nf]  = *(const float4*)&bias[gn0c[nf]];
    }

    #pragma unroll
    for (int mf = 0; mf < 4; ++mf) {
        const int gm = am0 + wr + mf * 16 + (lane & 15);
        // per-token scatter info (hoisted out of nf loop)
        size_t tokdst = 0;
        int wwi = 0, ntok = 0;
        if (MODE == 0) {
            wwi = gm / 49; ntok = gm - wwi * 49;
        } else if (MODE == 1) {
            int bb = gm / 3136; int rem = gm - bb * 3136;
            int wIdx = rem / 49; int n = rem - wIdx * 49;
            int wh = wIdx >> 3, ww2 = wIdx & 7;
            int yi = n / 7,     xi = n - yi * 7;
            int rr = wh * 7 + yi + 3; if (rr >= 56) rr -= 56;
            int cc = ww2 * 7 + xi + 3; if (cc >= 56) cc -= 56;
            tokdst = ((size_t)bb * 3136 + (size_t)rr * 56 + cc) * 384;
        }
        #pragma unroll
        for (int nf = 0; nf < 4; ++nf) {
            const int gn0 = gn0c[nf];
            float vals[4];
            #pragma unroll
            for (int r = 0; r < 4; ++r) vals[r] = acc[nf][mf][r] + ((const float*)&bvc[nf])[r];

            if (MODE == 0) {
                const int s3 = gn0 / 384; const int rem = gn0 - s3 * 384;
                const int hh = rem >> 5, d0 = rem & 31;
                size_t dst = (size_t)s3 * QKV_SEG
                           + ((size_t)(wwi * 12 + hh) * 49 + ntok) * 32 + d0;
                union { short h4[4]; uint2 u2; } pk;
                if (s3 == 0) {
                    #pragma unroll
                    for (int r = 0; r < 4; ++r)
                        pk.h4[r] = f2bs(vals[r] * 0.17677669529663687f);
                } else {
                    #pragma unroll
                    for (int r = 0; r < 4; ++r) pk.h4[r] = f2bs(vals[r]);
                }
                *(uint2*)&outb[dst] = pk.u2;
            } else if (MODE == 1) {
                size_t dst = tokdst + gn0;
                const float4 rv = *(const float4*)&resid[dst];
                float4 ov;
                ov.x = rv.x + vals[0]; ov.y = rv.y + vals[1];
                ov.z = rv.z + vals[2]; ov.w = rv.w + vals[3];
                *(float4*)&outf[dst] = ov;
            } else if (MODE == 2) {
                union { short h4[4]; unsigned long long u8; } pk;
                #pragma unroll
                for (int r = 0; r < 4; ++r) pk.h4[r] = f2bs(gelu_fast(vals[r]));
                // non-temporal: hid stream is single-consumer and >> L2
                __builtin_nontemporal_store(
                    pk.u8, (unsigned long long*)&outb[(size_t)gm * 1536 + gn0]);
            } else {
                size_t dst = (size_t)gm * 384 + gn0;
                const float4 rv = *(const float4*)&resid[dst];
                float4 ov;
                ov.x = rv.x + vals[0]; ov.y = rv.y + vals[1];
                ov.z = rv.z + vals[2]; ov.w = rv.w + vals[3];
                *(float4*)&outf[dst] = ov;
            }
        }
    }
}

// ---------------------------------------------------------------------------
// MFMA windowed attention. 4 waves/block, one (window,head) per wave.
// Swapped QK^T: S^T = mfma(A=K, B=Q) -> lane owns query col i. Softmax:
// 16 in-lane + shfl_xor(16,32). P -> LDS (XOR-swizzled). PV: O^T = mfma(V^T, P).
// ---------------------------------------------------------------------------
__global__ __launch_bounds__(256)
void attn_mfma(const bf16* __restrict__ q, const bf16* __restrict__ k,
               const bf16* __restrict__ v, const float* __restrict__ table,
               bf16* __restrict__ o)
{
    __shared__ bf16  vt_s[4][2048];   // per wave: V^T [32 d][64 j], swizzled
    __shared__ bf16  p_s[4][4096];    // per wave: P   [64 i][64 j], swizzled
    __shared__ float tbl_s[4][169];

    const int tid  = threadIdx.x;
    const int wid  = tid >> 6;
    const int lane = tid & 63;
    const int li = lane & 15, g = lane >> 4;
    const int gwh = blockIdx.x * 4 + wid;       // window*12 + head
    const int w = gwh / 12, h = gwh - w * 12;
    const int wIdx = w & 63;
    const int bh = wIdx >> 3, bw = wIdx & 7;
    const size_t base = (size_t)gwh * 1568;

    char* vt = (char*)vt_s[wid];
    char* ps = (char*)p_s[wid];

    for (int t = lane; t < 169; t += 64) tbl_s[wid][t] = table[t * 12 + h];

    {
        const int4 z = {0, 0, 0, 0};
        #pragma unroll
        for (int t = 0; t < 4; ++t) ((int4*)vt)[t * 64 + lane] = z;
        for (int t = lane; t < 196; t += 64) {
            const int j = t >> 2, d0 = (t & 3) * 8;
            bf16x8 row = *(const bf16x8*)&v[base + (size_t)j * 32 + d0];
            #pragma unroll
            for (int u = 0; u < 8; ++u) {
                const int d = d0 + u;
                int off = (d << 7) + (j << 1);
                off ^= (d & 7) << 4;
                *(short*)(vt + off) = row[u];
            }
        }
    }

    // QK^T (swapped): acc[mj][ni] = S^T[j][i]
    bf16x8 aK[4], bQ[4];
    const int koff = g * 8;
    #pragma unroll
    for (int mj = 0; mj < 4; ++mj)
        aK[mj] = *(const bf16x8*)&k[base + (size_t)(mj * 16 + li) * 32 + koff];
    #pragma unroll
    for (int ni = 0; ni < 4; ++ni)
        bQ[ni] = *(const bf16x8*)&q[base + (size_t)(ni * 16 + li) * 32 + koff];

    f32x4 acc[4][4];
    #pragma unroll
    for (int i = 0; i < 4; ++i)
        #pragma unroll
        for (int j = 0; j < 4; ++j) acc[i][j] = (f32x4)0.0f;
    #pragma unroll
    for (int mj = 0; mj < 4; ++mj)
        #pragma unroll
        for (int ni = 0; ni < 4; ++ni)
            acc[mj][ni] = __builtin_amdgcn_mfma_f32_16x16x32_bf16(
                aK[mj], bQ[ni], acc[mj][ni], 0, 0, 0);

    // softmax over j per query i
    const bool bndH = (bh == 7), bndW = (bw == 7);
    #pragma unroll
    for (int ni = 0; ni < 4; ++ni) {
        const int i = ni * 16 + li;
        const int yi = i / 7, xi = i - yi * 7;
        const int ri = (bndH ? (yi < 4 ? 3 : 6) : 0) + (bndW ? (xi < 4 ? 1 : 2) : 0);
        float mx = -1e30f;
        #pragma unroll
        for (int mj = 0; mj < 4; ++mj)
            #pragma unroll
            for (int r = 0; r < 4; ++r) {
                const int j = mj * 16 + g * 4 + r;
                const int yj = j / 7, xj = j - yj * 7;
                int ridx = (yi - yj + 6) * 13 + (xi - xj + 6);
                ridx = max(0, min(168, ridx));
                float val = acc[mj][ni][r] + tbl_s[wid][ridx];
                const int rj = (bndH ? (yj < 4 ? 3 : 6) : 0) + (bndW ? (xj < 4 ? 1 : 2) : 0);
                if (ri != rj) val -= 100.f;
                if (j >= 49) val = -1e30f;
                acc[mj][ni][r] = val;
                mx = fmaxf(mx, val);
            }
        mx = fmaxf(mx, __shfl_xor(mx, 16));
        mx = fmaxf(mx, __shfl_xor(mx, 32));
        float sum = 0.f;
        #pragma unroll
        for (int mj = 0; mj < 4; ++mj)
            #pragma unroll
            for (int r = 0; r < 4; ++r) {
                const float p = __expf(acc[mj][ni][r] - mx);
                acc[mj][ni][r] = p; sum += p;
            }
        sum += __shfl_xor(sum, 16);
        sum += __shfl_xor(sum, 32);
        const float inv = 1.f / sum;
        #pragma unroll
        for (int mj = 0; mj < 4; ++mj) {
            union { short h4[4]; uint2 u2; } pk;
            #pragma unroll
            for (int r = 0; r < 4; ++r) pk.h4[r] = f2bs(acc[mj][ni][r] * inv);
            int off = (i << 7) + ((mj * 16 + g * 4) << 1);
            off ^= (i & 7) << 4;
            *(uint2*)(ps + off) = pk.u2;
        }
    }

    // PV: acc2[md][ni] = O^T[d][i]
    f32x4 acc2[2][4];
    #pragma unroll
    for (int i = 0; i < 2; ++i)
        #pragma unroll
        for (int j = 0; j < 4; ++j) acc2[i][j] = (f32x4)0.0f;
    #pragma unroll
    for (int kk = 0; kk < 2; ++kk) {
        bf16x8 aV[2], bP[4];
        #pragma unroll
        for (int md = 0; md < 2; ++md) {
            const int d = md * 16 + li;
            int off = (d << 7) + kk * 64 + g * 16;
            off ^= (d & 7) << 4;
            aV[md] = *(const bf16x8*)(vt + off);
        }
        #pragma unroll
        for (int ni = 0; ni < 4; ++ni) {
            const int i = ni * 16 + li;
            int off = (i << 7) + kk * 64 + g * 16;
            off ^= (i & 7) << 4;
            bP[ni] = *(const bf16x8*)(ps + off);
        }
        #pragma unroll
        for (int md = 0; md < 2; ++md)
            #pragma unroll
            for (int ni = 0; ni < 4; ++ni)
                acc2[md][ni] = __builtin_amdgcn_mfma_f32_16x16x32_bf16(
                    aV[md], bP[ni], acc2[md][ni], 0, 0, 0);
    }

    // store O[i][d]
    const size_t obase = (size_t)w * 49 * 384 + h * 32;
    #pragma unroll
    for (int ni = 0; ni < 4; ++ni) {
        const int i = ni * 16 + li;
        if (i < 49) {
            #pragma unroll
            for (int md = 0; md < 2; ++md) {
                const int d0 = md * 16 + g * 4;
                union { short h4[4]; uint2 u2; } pk;
                #pragma unroll
                for (int r = 0; r < 4; ++r) pk.h4[r] = f2bs(acc2[md][ni][r]);
                *(uint2*)&o[obase + (size_t)i * 384 + d0] = pk.u2;
            }
        }
    }
}

// ---------------------------------------------------------------------------
extern "C" void kernel_launch(void* const* d_in, const int* in_sizes, int n_in,
                              void* d_out, int out_size, void* d_ws, size_t ws_size,
                              hipStream_t stream) {
    const float* x      = (const float*)d_in[0];
    const float* n1w    = (const float*)d_in[1];
    const float* n1b    = (const float*)d_in[2];
    const float* qkv_w  = (const float*)d_in[3];
    const float* qkv_b  = (const float*)d_in[4];
    const float* table  = (const float*)d_in[5];
    const float* proj_w = (const float*)d_in[6];
    const float* proj_b = (const float*)d_in[7];
    const float* n2w    = (const float*)d_in[8];
    const float* n2b    = (const float*)d_in[9];
    const float* fc1_w  = (const float*)d_in[10];
    const float* fc1_b  = (const float*)d_in[11];
    const float* fc2_w  = (const float*)d_in[12];
    const float* fc2_b  = (const float*)d_in[13];
    float* out = (float*)d_out;

    char* ws = (char*)d_ws;
    bf16* buf0 = (bf16*)ws;                              // TOK*384 bf16
    bf16* buf1 = (bf16*)(ws + 77070336);                 // qkv / hid
    bf16* wb   = (bf16*)(ws + 77070336 + 308281344);     // bf16 weights

    convert_w_kernel<<<1728, 256, 0, stream>>>(qkv_w, proj_w, fc1_w, fc2_w, wb);
    // 1) LN1 + roll + window partition -> buf0
    ln_kernel<true><<<TOK / 4, 256, 0, stream>>>(x, n1w, n1b, buf0);
    // 2) QKV GEMM -> buf1 (q|k|v, head-major); 392 M-tiles x 9 N-tiles
    gemm_bt<0, 384><<<392 * 9, 512, 0, stream>>>(buf0, wb, qkv_b,
                                                 buf1, nullptr, nullptr, 9);
    // 3) MFMA windowed attention -> buf0
    attn_mfma<<<2048 * 12 / 4, 256, 0, stream>>>(buf1, buf1 + QKV_SEG,
                                                 buf1 + 2 * QKV_SEG, table, buf0);
    // 4) proj GEMM + reverse/roll + residual -> out; 3 N-tiles
    gemm_bt<1, 384><<<392 * 3, 512, 0, stream>>>(buf0, wb + 442368, proj_b,
                                                 nullptr, out, x, 3);
    // 5) LN2(y) -> buf0
    ln_kernel<false><<<TOK / 4, 256, 0, stream>>>(out, n2w, n2b, buf0);
    // 6) fc1 + GELU -> buf1; 12 N-tiles
    gemm_bt<2, 384><<<392 * 12, 512, 0, stream>>>(buf0, wb + 589824, fc1_b,
                                                  buf1, nullptr, nullptr, 12);
    // 7) fc2 + residual (in-place on out); K=1536, 3 N-tiles
    gemm_bt<3, 1536><<<392 * 3, 512, 0, stream>>>(buf1, wb + 1179648, fc2_b,
                                                  nullptr, out, out, 3);
}

// Round 13
// 812.343 us; speedup vs baseline: 1.1570x; 1.0821x over previous
//
#include <hip/hip_runtime.h>
#include <hip/hip_bf16.h>
#include <math.h>

using bf16 = __hip_bfloat16;
typedef short bf16x8 __attribute__((ext_vector_type(8)));
typedef float f32x4 __attribute__((ext_vector_type(4)));

static constexpr int  TOK     = 100352;     // 32*56*56 tokens
static constexpr long QKV_SEG = 38535168L;  // TOK*384 elements per q/k/v segment

__device__ __forceinline__ float bf2f(short u) {
    return __uint_as_float(((unsigned)(unsigned short)u) << 16);
}
// fast RNE float->bf16
__device__ __forceinline__ short f2bs(float x) {
    unsigned u = __float_as_uint(x);
    u += 0x7FFF + ((u >> 16) & 1);
    return (short)(u >> 16);
}
// 1-ulp reciprocal (v_rcp_f32)
__device__ __forceinline__ float fast_rcp(float x) {
    float r;
    asm volatile("v_rcp_f32 %0, %1" : "=v"(r) : "v"(x));
    return r;
}
// async global->LDS, 16B per lane. LDS dest must be uniform base + lane*16.
__device__ __forceinline__ void gload16(const void* g, void* l) {
    __builtin_amdgcn_global_load_lds(
        (const __attribute__((address_space(1))) unsigned int*)g,
        (__attribute__((address_space(3))) unsigned int*)l, 16, 0, 0);
}
// tanh-form GELU: x * sigmoid(1.5957691x + 0.071354816x^3); max |err| ~1e-3
__device__ __forceinline__ float gelu_fast(float x) {
    const float x2 = x * x;
    const float t1 = x * x2;
    const float y  = fmaf(0.071354816222f, t1, 1.5957691216f * x);
    const float e  = __expf(-y);
    return x * fast_rcp(1.f + e);
}

// ---------------------------------------------------------------------------
// Pre-convert all fp32 weights to bf16 (once per launch, ~7MB traffic).
// layout: qkv[0,442368) proj[442368,589824) fc1[589824,1179648) fc2[1179648,1769472)
// ---------------------------------------------------------------------------
__global__ __launch_bounds__(256)
void convert_w_kernel(const float* __restrict__ qkv_w, const float* __restrict__ proj_w,
                      const float* __restrict__ fc1_w, const float* __restrict__ fc2_w,
                      bf16* __restrict__ out)
{
    const int i4 = (blockIdx.x * 256 + threadIdx.x) * 4;
    if (i4 >= 1769472) return;
    const float* src; int off;
    if (i4 < 442368)       { src = qkv_w;  off = i4; }
    else if (i4 < 589824)  { src = proj_w; off = i4 - 442368; }
    else if (i4 < 1179648) { src = fc1_w;  off = i4 - 589824; }
    else                   { src = fc2_w;  off = i4 - 1179648; }
    const float4 v = *(const float4*)&src[off];
    out[i4+0] = __float2bfloat16(v.x);
    out[i4+1] = __float2bfloat16(v.y);
    out[i4+2] = __float2bfloat16(v.z);
    out[i4+3] = __float2bfloat16(v.w);
}

// ---------------------------------------------------------------------------
// LayerNorm over C=384, one wave per token. WINDOWED: dst order is
// (b, window, intra-window) after roll(-3,-3); source is original x.
// ---------------------------------------------------------------------------
template<bool WINDOWED>
__global__ __launch_bounds__(256)
void ln_kernel(const float* __restrict__ x, const float* __restrict__ gw,
               const float* __restrict__ gb, bf16* __restrict__ out)
{
    const int wave = threadIdx.x >> 6;
    const int lane = threadIdx.x & 63;
    const long t = (long)blockIdx.x * 4 + wave;
    size_t src;
    if (WINDOWED) {
        int bb = (int)(t / 3136); int rem = (int)(t - (long)bb * 3136);
        int wIdx = rem / 49;      int n = rem - wIdx * 49;
        int wh = wIdx >> 3, ww = wIdx & 7;
        int yi = n / 7,     xi = n - yi * 7;
        int r = wh * 7 + yi + 3; if (r >= 56) r -= 56;
        int c = ww * 7 + xi + 3; if (c >= 56) c -= 56;
        src = ((size_t)bb * 3136 + (size_t)r * 56 + c) * 384;
    } else {
        src = (size_t)t * 384;
    }
    float v[6]; float s = 0.f, sq = 0.f;
    #pragma unroll
    for (int kk = 0; kk < 6; ++kk) {
        v[kk] = x[src + lane + 64 * kk];
        s += v[kk]; sq += v[kk] * v[kk];
    }
    #pragma unroll
    for (int o = 32; o > 0; o >>= 1) { s += __shfl_xor(s, o); sq += __shfl_xor(sq, o); }
    const float m   = s * (1.f / 384.f);
    const float var = sq * (1.f / 384.f) - m * m;
    const float rs  = rsqrtf(var + 1e-5f);
    #pragma unroll
    for (int kk = 0; kk < 6; ++kk) {
        int ch = lane + 64 * kk;
        out[(size_t)t * 384 + ch] = __float2bfloat16((v[kk] - m) * rs * gw[ch] + gb[ch]);
    }
}

// ---------------------------------------------------------------------------
// GEMM: C[M,N] = A[M,K](bf16) @ W[N,K]^T(bf16) + bias.  (round-10 structure,
// best measured: fc1 210us, MfmaUtil 24%, conflicts 0)
// BM=256 x BN=128 tile, BK=64, 8 waves, wave tile 64x64 (16x16x32 MFMA,
// 4x4 frags). Single-buffered 48 KB LDS; T2 XOR swizzle both-sides; swapped
// MFMA operands -> lane holds 4 consecutive output features; 32-bit epilogue.
// NOTE: nt-stores on MODE 2 tried (r12) -> WRITE_SIZE doubled, reverted.
// ---------------------------------------------------------------------------
template<int MODE, int K>
__global__ __launch_bounds__(512)
void gemm_bt(const bf16* __restrict__ A, const bf16* __restrict__ W,
             const float* __restrict__ bias, bf16* __restrict__ outb,
             float* __restrict__ outf, const float* __restrict__ resid,
             int tilesN)
{
    __shared__ bf16 As[256 * 64];   // 32 KB
    __shared__ bf16 Bs[128 * 64];   // 16 KB
    const int nwg = gridDim.x;
    const int b0  = blockIdx.x;
    const int swz = (b0 & 7) * (nwg >> 3) + (b0 >> 3);
    const int tm = swz / tilesN;
    const int tn = swz - tm * tilesN;
    const int tid  = threadIdx.x;
    const int lane = tid & 63;
    const int wid  = tid >> 6;
    const int wr = (wid >> 1) << 6;   // M offset of wave tile: 0..192
    const int wc = (wid & 1) << 6;    // N offset of wave tile: 0/64
    const int sr = tid >> 3;          // staging row 0..63
    const int sc = (tid & 7) * 8;     // staging LDS col, step 8
    const int scs = sc ^ ((sr & 7) << 3);   // pre-swizzled SOURCE col

    f32x4 acc[4][4];                  // [nf][mf]
    #pragma unroll
    for (int i = 0; i < 4; ++i)
        #pragma unroll
        for (int j = 0; j < 4; ++j) acc[i][j] = (f32x4)0.0f;

    const int am0 = tm * 256;
    const int bn0 = tn * 128;
    const bf16* Ab = A + (size_t)am0 * K + scs;   // + row*K + k0
    const bf16* Wb = W + (size_t)bn0 * K + scs;

    const int rophase = (lane & 7) << 3;   // read-side swizzle phase
    const int kbase   = (lane >> 4) * 8;

    for (int k0 = 0; k0 < K; k0 += 64) {
        #pragma unroll
        for (int p = 0; p < 4; ++p) {
            const int row = p * 64 + sr;
            gload16(&Ab[(size_t)row * K + k0], &As[row * 64 + sc]);
        }
        #pragma unroll
        for (int p = 0; p < 2; ++p) {
            const int row = p * 64 + sr;
            gload16(&Wb[(size_t)row * K + k0], &Bs[row * 64 + sc]);
        }
        __syncthreads();
        #pragma unroll
        for (int kk = 0; kk < 2; ++kk) {
            const int kofs = (kk * 32 + kbase) ^ rophase;
            bf16x8 aF[4], bF[4];
            #pragma unroll
            for (int mi = 0; mi < 4; ++mi)
                aF[mi] = *(const bf16x8*)&As[(wr + mi * 16 + (lane & 15)) * 64 + kofs];
            #pragma unroll
            for (int ni = 0; ni < 4; ++ni)
                bF[ni] = *(const bf16x8*)&Bs[(wc + ni * 16 + (lane & 15)) * 64 + kofs];
            #pragma unroll
            for (int ni = 0; ni < 4; ++ni)
                #pragma unroll
                for (int mi = 0; mi < 4; ++mi)
                    acc[ni][mi] = __builtin_amdgcn_mfma_f32_16x16x32_bf16(
                        bF[ni], aF[mi], acc[ni][mi], 0, 0, 0);
        }
        __syncthreads();
    }

    // ---- epilogue: lane holds features gn0..gn0+3 at token gm (32-bit math) ----
    const int g4 = (lane >> 4) << 2;
    int    gn0c[4];
    float4 bvc[4];
    #pragma unroll
    for (int nf = 0; nf < 4; ++nf) {
        gn0c[nf] = bn0 + wc + nf * 16 + g4;     // 4-aligned
        bvc[nf]  = *(const float4*)&bias[gn0c[nf]];
    }

    #pragma unroll
    for (int mf = 0; mf < 4; ++mf) {
        const int gm = am0 + wr + mf * 16 + (lane & 15);
        // per-token scatter info (hoisted out of nf loop)
        size_t tokdst = 0;
        int wwi = 0, ntok = 0;
        if (MODE == 0) {
            wwi = gm / 49; ntok = gm - wwi * 49;
        } else if (MODE == 1) {
            int bb = gm / 3136; int rem = gm - bb * 3136;
            int wIdx = rem / 49; int n = rem - wIdx * 49;
            int wh = wIdx >> 3, ww2 = wIdx & 7;
            int yi = n / 7,     xi = n - yi * 7;
            int rr = wh * 7 + yi + 3; if (rr >= 56) rr -= 56;
            int cc = ww2 * 7 + xi + 3; if (cc >= 56) cc -= 56;
            tokdst = ((size_t)bb * 3136 + (size_t)rr * 56 + cc) * 384;
        }
        #pragma unroll
        for (int nf = 0; nf < 4; ++nf) {
            const int gn0 = gn0c[nf];
            float vals[4];
            #pragma unroll
            for (int r = 0; r < 4; ++r) vals[r] = acc[nf][mf][r] + ((const float*)&bvc[nf])[r];

            if (MODE == 0) {
                const int s3 = gn0 / 384; const int rem = gn0 - s3 * 384;
                const int hh = rem >> 5, d0 = rem & 31;
                size_t dst = (size_t)s3 * QKV_SEG
                           + ((size_t)(wwi * 12 + hh) * 49 + ntok) * 32 + d0;
                union { short h4[4]; uint2 u2; } pk;
                if (s3 == 0) {
                    #pragma unroll
                    for (int r = 0; r < 4; ++r)
                        pk.h4[r] = f2bs(vals[r] * 0.17677669529663687f);
                } else {
                    #pragma unroll
                    for (int r = 0; r < 4; ++r) pk.h4[r] = f2bs(vals[r]);
                }
                *(uint2*)&outb[dst] = pk.u2;
            } else if (MODE == 1) {
                size_t dst = tokdst + gn0;
                const float4 rv = *(const float4*)&resid[dst];
                float4 ov;
                ov.x = rv.x + vals[0]; ov.y = rv.y + vals[1];
                ov.z = rv.z + vals[2]; ov.w = rv.w + vals[3];
                *(float4*)&outf[dst] = ov;
            } else if (MODE == 2) {
                union { short h4[4]; uint2 u2; } pk;
                #pragma unroll
                for (int r = 0; r < 4; ++r) pk.h4[r] = f2bs(gelu_fast(vals[r]));
                *(uint2*)&outb[(size_t)gm * 1536 + gn0] = pk.u2;
            } else {
                size_t dst = (size_t)gm * 384 + gn0;
                const float4 rv = *(const float4*)&resid[dst];
                float4 ov;
                ov.x = rv.x + vals[0]; ov.y = rv.y + vals[1];
                ov.z = rv.z + vals[2]; ov.w = rv.w + vals[3];
                *(float4*)&outf[dst] = ov;
            }
        }
    }
}

// ---------------------------------------------------------------------------
// MFMA windowed attention. 4 waves/block, one (window,head) per wave.
// Swapped QK^T: S^T = mfma(A=K, B=Q) -> lane owns query col i. Softmax:
// 16 in-lane + shfl_xor(16,32). P -> LDS (XOR-swizzled). PV: O^T = mfma(V^T, P).
// ---------------------------------------------------------------------------
__global__ __launch_bounds__(256)
void attn_mfma(const bf16* __restrict__ q, const bf16* __restrict__ k,
               const bf16* __restrict__ v, const float* __restrict__ table,
               bf16* __restrict__ o)
{
    __shared__ bf16  vt_s[4][2048];   // per wave: V^T [32 d][64 j], swizzled
    __shared__ bf16  p_s[4][4096];    // per wave: P   [64 i][64 j], swizzled
    __shared__ float tbl_s[4][169];

    const int tid  = threadIdx.x;
    const int wid  = tid >> 6;
    const int lane = tid & 63;
    const int li = lane & 15, g = lane >> 4;
    const int gwh = blockIdx.x * 4 + wid;       // window*12 + head
    const int w = gwh / 12, h = gwh - w * 12;
    const int wIdx = w & 63;
    const int bh = wIdx >> 3, bw = wIdx & 7;
    const size_t base = (size_t)gwh * 1568;

    char* vt = (char*)vt_s[wid];
    char* ps = (char*)p_s[wid];

    for (int t = lane; t < 169; t += 64) tbl_s[wid][t] = table[t * 12 + h];

    {
        const int4 z = {0, 0, 0, 0};
        #pragma unroll
        for (int t = 0; t < 4; ++t) ((int4*)vt)[t * 64 + lane] = z;
        for (int t = lane; t < 196; t += 64) {
            const int j = t >> 2, d0 = (t & 3) * 8;
            bf16x8 row = *(const bf16x8*)&v[base + (size_t)j * 32 + d0];
            #pragma unroll
            for (int u = 0; u < 8; ++u) {
                const int d = d0 + u;
                int off = (d << 7) + (j << 1);
                off ^= (d & 7) << 4;
                *(short*)(vt + off) = row[u];
            }
        }
    }

    // QK^T (swapped): acc[mj][ni] = S^T[j][i]
    bf16x8 aK[4], bQ[4];
    const int koff = g * 8;
    #pragma unroll
    for (int mj = 0; mj < 4; ++mj)
        aK[mj] = *(const bf16x8*)&k[base + (size_t)(mj * 16 + li) * 32 + koff];
    #pragma unroll
    for (int ni = 0; ni < 4; ++ni)
        bQ[ni] = *(const bf16x8*)&q[base + (size_t)(ni * 16 + li) * 32 + koff];

    f32x4 acc[4][4];
    #pragma unroll
    for (int i = 0; i < 4; ++i)
        #pragma unroll
        for (int j = 0; j < 4; ++j) acc[i][j] = (f32x4)0.0f;
    #pragma unroll
    for (int mj = 0; mj < 4; ++mj)
        #pragma unroll
        for (int ni = 0; ni < 4; ++ni)
            acc[mj][ni] = __builtin_amdgcn_mfma_f32_16x16x32_bf16(
                aK[mj], bQ[ni], acc[mj][ni], 0, 0, 0);

    // softmax over j per query i
    const bool bndH = (bh == 7), bndW = (bw == 7);
    #pragma unroll
    for (int ni = 0; ni < 4; ++ni) {
        const int i = ni * 16 + li;
        const int yi = i / 7, xi = i - yi * 7;
        const int ri = (bndH ? (yi < 4 ? 3 : 6) : 0) + (bndW ? (xi < 4 ? 1 : 2) : 0);
        float mx = -1e30f;
        #pragma unroll
        for (int mj = 0; mj < 4; ++mj)
            #pragma unroll
            for (int r = 0; r < 4; ++r) {
                const int j = mj * 16 + g * 4 + r;
                const int yj = j / 7, xj = j - yj * 7;
                int ridx = (yi - yj + 6) * 13 + (xi - xj + 6);
                ridx = max(0, min(168, ridx));
                float val = acc[mj][ni][r] + tbl_s[wid][ridx];
                const int rj = (bndH ? (yj < 4 ? 3 : 6) : 0) + (bndW ? (xj < 4 ? 1 : 2) : 0);
                if (ri != rj) val -= 100.f;
                if (j >= 49) val = -1e30f;
                acc[mj][ni][r] = val;
                mx = fmaxf(mx, val);
            }
        mx = fmaxf(mx, __shfl_xor(mx, 16));
        mx = fmaxf(mx, __shfl_xor(mx, 32));
        float sum = 0.f;
        #pragma unroll
        for (int mj = 0; mj < 4; ++mj)
            #pragma unroll
            for (int r = 0; r < 4; ++r) {
                const float p = __expf(acc[mj][ni][r] - mx);
                acc[mj][ni][r] = p; sum += p;
            }
        sum += __shfl_xor(sum, 16);
        sum += __shfl_xor(sum, 32);
        const float inv = 1.f / sum;
        #pragma unroll
        for (int mj = 0; mj < 4; ++mj) {
            union { short h4[4]; uint2 u2; } pk;
            #pragma unroll
            for (int r = 0; r < 4; ++r) pk.h4[r] = f2bs(acc[mj][ni][r] * inv);
            int off = (i << 7) + ((mj * 16 + g * 4) << 1);
            off ^= (i & 7) << 4;
            *(uint2*)(ps + off) = pk.u2;
        }
    }

    // PV: acc2[md][ni] = O^T[d][i]
    f32x4 acc2[2][4];
    #pragma unroll
    for (int i = 0; i < 2; ++i)
        #pragma unroll
        for (int j = 0; j < 4; ++j) acc2[i][j] = (f32x4)0.0f;
    #pragma unroll
    for (int kk = 0; kk < 2; ++kk) {
        bf16x8 aV[2], bP[4];
        #pragma unroll
        for (int md = 0; md < 2; ++md) {
            const int d = md * 16 + li;
            int off = (d << 7) + kk * 64 + g * 16;
            off ^= (d & 7) << 4;
            aV[md] = *(const bf16x8*)(vt + off);
        }
        #pragma unroll
        for (int ni = 0; ni < 4; ++ni) {
            const int i = ni * 16 + li;
            int off = (i << 7) + kk * 64 + g * 16;
            off ^= (i & 7) << 4;
            bP[ni] = *(const bf16x8*)(ps + off);
        }
        #pragma unroll
        for (int md = 0; md < 2; ++md)
            #pragma unroll
            for (int ni = 0; ni < 4; ++ni)
                acc2[md][ni] = __builtin_amdgcn_mfma_f32_16x16x32_bf16(
                    aV[md], bP[ni], acc2[md][ni], 0, 0, 0);
    }

    // store O[i][d]
    const size_t obase = (size_t)w * 49 * 384 + h * 32;
    #pragma unroll
    for (int ni = 0; ni < 4; ++ni) {
        const int i = ni * 16 + li;
        if (i < 49) {
            #pragma unroll
            for (int md = 0; md < 2; ++md) {
                const int d0 = md * 16 + g * 4;
                union { short h4[4]; uint2 u2; } pk;
                #pragma unroll
                for (int r = 0; r < 4; ++r) pk.h4[r] = f2bs(acc2[md][ni][r]);
                *(uint2*)&o[obase + (size_t)i * 384 + d0] = pk.u2;
            }
        }
    }
}

// ---------------------------------------------------------------------------
extern "C" void kernel_launch(void* const* d_in, const int* in_sizes, int n_in,
                              void* d_out, int out_size, void* d_ws, size_t ws_size,
                              hipStream_t stream) {
    const float* x      = (const float*)d_in[0];
    const float* n1w    = (const float*)d_in[1];
    const float* n1b    = (const float*)d_in[2];
    const float* qkv_w  = (const float*)d_in[3];
    const float* qkv_b  = (const float*)d_in[4];
    const float* table  = (const float*)d_in[5];
    const float* proj_w = (const float*)d_in[6];
    const float* proj_b = (const float*)d_in[7];
    const float* n2w    = (const float*)d_in[8];
    const float* n2b    = (const float*)d_in[9];
    const float* fc1_w  = (const float*)d_in[10];
    const float* fc1_b  = (const float*)d_in[11];
    const float* fc2_w  = (const float*)d_in[12];
    const float* fc2_b  = (const float*)d_in[13];
    float* out = (float*)d_out;

    char* ws = (char*)d_ws;
    bf16* buf0 = (bf16*)ws;                              // TOK*384 bf16
    bf16* buf1 = (bf16*)(ws + 77070336);                 // qkv / hid
    bf16* wb   = (bf16*)(ws + 77070336 + 308281344);     // bf16 weights

    convert_w_kernel<<<1728, 256, 0, stream>>>(qkv_w, proj_w, fc1_w, fc2_w, wb);
    // 1) LN1 + roll + window partition -> buf0
    ln_kernel<true><<<TOK / 4, 256, 0, stream>>>(x, n1w, n1b, buf0);
    // 2) QKV GEMM -> buf1 (q|k|v, head-major); 392 M-tiles x 9 N-tiles
    gemm_bt<0, 384><<<392 * 9, 512, 0, stream>>>(buf0, wb, qkv_b,
                                                 buf1, nullptr, nullptr, 9);
    // 3) MFMA windowed attention -> buf0
    attn_mfma<<<2048 * 12 / 4, 256, 0, stream>>>(buf1, buf1 + QKV_SEG,
                                                 buf1 + 2 * QKV_SEG, table, buf0);
    // 4) proj GEMM + reverse/roll + residual -> out; 3 N-tiles
    gemm_bt<1, 384><<<392 * 3, 512, 0, stream>>>(buf0, wb + 442368, proj_b,
                                                 nullptr, out, x, 3);
    // 5) LN2(y) -> buf0
    ln_kernel<false><<<TOK / 4, 256, 0, stream>>>(out, n2w, n2b, buf0);
    // 6) fc1 + GELU -> buf1; 12 N-tiles
    gemm_bt<2, 384><<<392 * 12, 512, 0, stream>>>(buf0, wb + 589824, fc1_b,
                                                  buf1, nullptr, nullptr, 12);
    // 7) fc2 + residual (in-place on out); K=1536, 3 N-tiles
    gemm_bt<3, 1536><<<392 * 3, 512, 0, stream>>>(buf1, wb + 1179648, fc2_b,
                                                  nullptr, out, out, 3);
}